// Round 7
// baseline (742.042 us; speedup 1.0000x reference)
//
#include <hip/hip_runtime.h>
#include <math.h>

#define NNODES 100000
#define NEDGES 3200000
#define F 128
#define NPB 512
#define NB ((NNODES + NPB - 1) / NPB)   // 196 buckets
#define CAP 20480                        // slots per bucket (mean 16326, 32 sigma margin)
#define T2 8192

typedef __attribute__((ext_vector_type(8))) short short8;
typedef __attribute__((ext_vector_type(4))) float f32x4;

__device__ __forceinline__ unsigned short f2bf(float f) {
    unsigned u = __float_as_uint(f);
    unsigned r = u + 0x7fff + ((u >> 16) & 1);
    return (unsigned short)(r >> 16);
}
__device__ __forceinline__ float bflo(unsigned u) { return __uint_as_float(u << 16); }
__device__ __forceinline__ float bfhi(unsigned u) { return __uint_as_float(u & 0xffff0000u); }

// ---------------- cursor init (CAP-strided bucket bases) ----------------

__global__ void init_cursors_kernel(int* __restrict__ dcur, int* __restrict__ scur) {
    int b = blockIdx.x * 256 + threadIdx.x;
    if (b < NB) { dcur[b] = b * CAP; scur[b] = b * CAP; }
}

// ---------------- dual binning: one edge read -> dst-keyed + src-keyed bins ----------------

__global__ __launch_bounds__(256) void dual_bin_kernel(const int* __restrict__ src,
                                                       const int* __restrict__ dst,
                                                       int* __restrict__ dcur,
                                                       int* __restrict__ scur,
                                                       unsigned* __restrict__ epk,
                                                       unsigned short* __restrict__ esl) {
    __shared__ unsigned pk[T2];
    __shared__ unsigned short sl[T2];
    __shared__ unsigned char db[T2], sb[T2];
    __shared__ int dh[NB], dbase[NB], dlc[NB];
    __shared__ int sh[NB], sbase[NB], slc[NB];
    int t = threadIdx.x;
    for (int i = t; i < NB; i += 256) { dh[i] = 0; dlc[i] = 0; sh[i] = 0; slc[i] = 0; }
    __syncthreads();
    int e0 = blockIdx.x * T2;
    int n = min(T2, NEDGES - e0);
    for (int i = t; i < n; i += 256) {
        int s = src[e0 + i], d = dst[e0 + i];
        int bd = d >> 9, bs = s >> 9;
        pk[i] = (unsigned)s | ((unsigned)(d & 511) << 17);
        sl[i] = (unsigned short)(s & 511);
        db[i] = (unsigned char)bd;
        sb[i] = (unsigned char)bs;
        atomicAdd(&dh[bd], 1);
        atomicAdd(&sh[bs], 1);
    }
    __syncthreads();
    for (int b = t; b < NB; b += 256) {
        if (dh[b]) dbase[b] = atomicAdd(&dcur[b], dh[b]);
        if (sh[b]) sbase[b] = atomicAdd(&scur[b], sh[b]);
    }
    __syncthreads();
    for (int i = t; i < n; i += 256) {
        int b = db[i];
        epk[dbase[b] + atomicAdd(&dlc[b], 1)] = pk[i];
    }
    for (int i = t; i < n; i += 256) {
        int b = sb[i];
        esl[sbase[b] + atomicAdd(&slc[b], 1)] = sl[i];
    }
}

// ---------------- out-degree -> out_norm (per-bucket LDS histogram) ----------------

__global__ __launch_bounds__(512) void src_hist_kernel(const unsigned short* __restrict__ esl,
                                                       const int* __restrict__ scur,
                                                       float* __restrict__ out_norm) {
    __shared__ int cnt[NPB];
    int t = threadIdx.x, b = blockIdx.x;
    cnt[t] = 0;
    __syncthreads();
    int e0 = b * CAP, e1 = scur[b];
    for (int i = e0 + t; i < e1; i += 512) atomicAdd(&cnt[esl[i]], 1);
    __syncthreads();
    int node = b * NPB + t;
    if (node < NNODES) out_norm[node] = rsqrtf((float)max(cnt[t], 1));
}

// ---------------- per-bucket fine CSR + in_norm (all-LDS cursors) ----------------

__global__ __launch_bounds__(512) void bucket_csr_kernel(const unsigned* __restrict__ epk,
                                                         const int* __restrict__ dcur,
                                                         int2* __restrict__ row_span,
                                                         float* __restrict__ in_norm,
                                                         int* __restrict__ csr_src) {
    __shared__ int hist[NPB], off[NPB], lcur[NPB];
    int t = threadIdx.x, b = blockIdx.x;
    hist[t] = 0; lcur[t] = 0;
    __syncthreads();
    int e0 = b * CAP, e1 = dcur[b];
    for (int i = e0 + t; i < e1; i += 512)
        atomicAdd(&hist[epk[i] >> 17], 1);
    __syncthreads();
    int h = hist[t];
    off[t] = h;
    __syncthreads();
    for (int d = 1; d < NPB; d <<= 1) {
        int u = (t >= d) ? off[t - d] : 0;
        __syncthreads();
        off[t] += u;
        __syncthreads();
    }
    int excl = off[t] - h;
    int node = b * NPB + t;
    if (node < NNODES) {
        row_span[node] = make_int2(e0 + excl, e0 + excl + h);
        in_norm[node] = rsqrtf((float)max(h, 1));
    }
    __syncthreads();
    off[t] = excl;
    __syncthreads();
    for (int i = e0 + t; i < e1; i += 512) {
        unsigned p = epk[i];
        int dl = p >> 17;
        csr_src[e0 + off[dl] + atomicAdd(&lcur[dl], 1)] = (int)(p & 0x1FFFF);
    }
}

// ---------------- x * out_norm -> bf16, slice-major [8][N][8 uints] ----------------
// slice s, uint q of row = feats (16s+2q, 16s+2q+1); with l = s*8+q this is feats (2l, 2l+1)

__global__ __launch_bounds__(256) void scale_slice_kernel(const float* __restrict__ x,
                                                          const float* __restrict__ out_norm,
                                                          unsigned* __restrict__ hsS) {
    int tid = blockIdx.x * 256 + threadIdx.x;
    if (tid >= NNODES * 64) return;
    int row = tid >> 6, l = tid & 63;
    int s = l >> 3, q = l & 7;
    float nrm = out_norm[row];
    float2 v = *(const float2*)(x + (size_t)row * F + 2 * l);
    hsS[((size_t)s * NNODES + row) * 8 + q] =
        (unsigned)f2bf(v.x * nrm) | ((unsigned)f2bf(v.y * nrm) << 16);
}

// ---------------- pack all 4 weight matrices into MFMA B-fragments ----------------
// Bp[(c*4+s)*64+lane] = W[s*32+(lane>>4)*8+j][c*16+(lane&15)]

__global__ void pack_all_kernel(const float* __restrict__ W1, const float* __restrict__ W2,
                                const float* __restrict__ Wm1, const float* __restrict__ Wm2,
                                short8* __restrict__ Wp) {
    int idx = blockIdx.x * 256 + threadIdx.x;
    if (idx >= 7168) return;
    const float* W; int ncol, base;
    if (idx < 2048)      { W = W1;  ncol = 128; base = 0; }
    else if (idx < 4096) { W = W2;  ncol = 128; base = 2048; }
    else if (idx < 6144) { W = Wm1; ncol = 128; base = 4096; }
    else                 { W = Wm2; ncol = 64;  base = 6144; }
    int li = idx - base;
    int lane = li & 63, s = (li >> 6) & 3, c = li >> 8;
    int nn = c * 16 + (lane & 15);
    int k0 = s * 32 + (lane >> 4) * 8;
    short8 v;
#pragma unroll
    for (int j = 0; j < 8; j++) v[j] = (short)f2bf(W[(size_t)(k0 + j) * ncol + nn]);
    Wp[idx] = v;
}

// ---------------- sliced aggregation: blockIdx.y = slice (3.2 MB working set) ----------------
// 8 lane-groups of 8; each group gathers one edge's 32B slice; xor-shuffle combine.

__global__ __launch_bounds__(256) void aggregate_slice_kernel(const unsigned* __restrict__ hsS,
                                                              const int2* __restrict__ row_span,
                                                              const int* __restrict__ csr_src,
                                                              const float* __restrict__ in_norm,
                                                              unsigned* __restrict__ outS) {
    int wave = threadIdx.x >> 6;
    int lane = threadIdx.x & 63;
    int g = lane >> 3, q = lane & 7;
    int node = blockIdx.x * 4 + wave;
    int s = blockIdx.y;
    const unsigned* hs = hsS + (size_t)s * NNODES * 8;
    int2 sp = row_span[node];
    int beg = sp.x, end = sp.y;
    float a0 = 0.f, a1 = 0.f;
    for (int j = beg; j < end; j += 32) {
#pragma unroll
        for (int t = 0; t < 4; t++) {
            int idx = j + t * 8 + g;
            int sidx = csr_src[min(idx, end - 1)];
            unsigned u = hs[(size_t)sidx * 8 + q];
            if (idx >= end) u = 0u;
            a0 += bflo(u);
            a1 += bfhi(u);
        }
    }
    a0 += __shfl_xor(a0, 8);  a1 += __shfl_xor(a1, 8);
    a0 += __shfl_xor(a0, 16); a1 += __shfl_xor(a1, 16);
    a0 += __shfl_xor(a0, 32); a1 += __shfl_xor(a1, 32);
    if (lane < 8) {
        float inn = in_norm[node];
        outS[((size_t)s * NNODES + node) * 8 + lane] =
            (unsigned)f2bf(a0 * inn) | ((unsigned)f2bf(a1 * inn) << 16);
    }
}

// ---------------- MFMA GEMM: relu(A@W+b) [*out_norm] ----------------
// ASLICE: A is slice-major shorts; CSLICE: store slice-major (else row-major)

template <int SCALE, int CSLICE>
__global__ __launch_bounds__(256) void gemm_mfma_kernel(const unsigned short* __restrict__ A,
                                                        const short8* __restrict__ Bp,
                                                        const float* __restrict__ bias,
                                                        const float* __restrict__ out_norm,
                                                        unsigned short* __restrict__ Cout, int nrows) {
    int w = threadIdx.x >> 6, lane = threadIdx.x & 63;
    int m = lane & 15, quad = lane >> 4;
    int row0 = blockIdx.x * 64 + w * 16;

    int arow = min(row0 + m, nrows - 1);
    short8 afrag[4];
#pragma unroll
    for (int s = 0; s < 4; s++) {
        int sl = 2 * s + (quad >> 1);           // slice of feats [s*32+quad*8, +8)
        int off = (quad & 1) * 8;
        afrag[s] = *(const short8*)(A + ((size_t)sl * NNODES + arow) * 16 + off);
    }

    int baseRow = row0 + quad * 4;
    float nrm[4];
    if (SCALE) {
#pragma unroll
        for (int r = 0; r < 4; r++) nrm[r] = out_norm[min(baseRow + r, nrows - 1)];
    }

#pragma unroll
    for (int c = 0; c < 8; c++) {
        f32x4 acc = {0.f, 0.f, 0.f, 0.f};
#pragma unroll
        for (int s = 0; s < 4; s++) {
            short8 b = Bp[(c * 4 + s) * 64 + lane];
            acc = __builtin_amdgcn_mfma_f32_16x16x32_bf16(afrag[s], b, acc, 0, 0, 0);
        }
        float bc = bias[c * 16 + m];
#pragma unroll
        for (int r = 0; r < 4; r++) {
            int row = baseRow + r;
            if (row < nrows) {
                float v = fmaxf(acc[r] + bc, 0.f);
                if (SCALE) v *= nrm[r];
                if (CSLICE)
                    Cout[((size_t)c * NNODES + row) * 16 + m] = f2bf(v);   // slice c, offset m
                else
                    Cout[(size_t)row * F + c * 16 + m] = f2bf(v);
            }
        }
    }
}

// ---------------- fused MLP head: sigmoid(relu(A@Wm1+bm1)@Wm2+bm2), A row-major ----------------

__global__ __launch_bounds__(256) void mlp_fused_kernel(const unsigned short* __restrict__ A,
                                                        const short8* __restrict__ Bp1,
                                                        const float* __restrict__ bm1,
                                                        const short8* __restrict__ Bp2,
                                                        const float* __restrict__ bm2,
                                                        float* __restrict__ out, int nrows) {
    __shared__ unsigned short h3[4][16][136];
    int w = threadIdx.x >> 6, lane = threadIdx.x & 63;
    int m = lane & 15, quad = lane >> 4;
    int row0 = blockIdx.x * 64 + w * 16;

    int arow = min(row0 + m, nrows - 1);
    short8 afrag[4];
#pragma unroll
    for (int s = 0; s < 4; s++)
        afrag[s] = *(const short8*)(A + (size_t)arow * F + s * 32 + quad * 8);

#pragma unroll
    for (int c = 0; c < 8; c++) {
        f32x4 acc = {0.f, 0.f, 0.f, 0.f};
#pragma unroll
        for (int s = 0; s < 4; s++) {
            short8 b = Bp1[(c * 4 + s) * 64 + lane];
            acc = __builtin_amdgcn_mfma_f32_16x16x32_bf16(afrag[s], b, acc, 0, 0, 0);
        }
        float bc = bm1[c * 16 + m];
#pragma unroll
        for (int r = 0; r < 4; r++)
            h3[w][quad * 4 + r][c * 16 + m] = f2bf(fmaxf(acc[r] + bc, 0.f));
    }
    __syncthreads();

    short8 a2[4];
#pragma unroll
    for (int s = 0; s < 4; s++)
        a2[s] = *(const short8*)(&h3[w][m][s * 32 + quad * 8]);

    int baseRow = row0 + quad * 4;
#pragma unroll
    for (int c2 = 0; c2 < 4; c2++) {
        f32x4 acc = {0.f, 0.f, 0.f, 0.f};
#pragma unroll
        for (int s = 0; s < 4; s++) {
            short8 b = Bp2[(c2 * 4 + s) * 64 + lane];
            acc = __builtin_amdgcn_mfma_f32_16x16x32_bf16(a2[s], b, acc, 0, 0, 0);
        }
        float bc = bm2[c2 * 16 + m];
#pragma unroll
        for (int r = 0; r < 4; r++) {
            int row = baseRow + r;
            if (row < nrows)
                out[(size_t)row * 64 + c2 * 16 + m] = 1.f / (1.f + __expf(-(acc[r] + bc)));
        }
    }
}

// ---------------- launch ----------------

extern "C" void kernel_launch(void* const* d_in, const int* in_sizes, int n_in,
                              void* d_out, int out_size, void* d_ws, size_t ws_size,
                              hipStream_t stream) {
    const float* x   = (const float*)d_in[0];
    const int* src   = (const int*)d_in[1];
    const int* dst   = (const int*)d_in[2];
    const float* W1  = (const float*)d_in[3];
    const float* b1  = (const float*)d_in[4];
    const float* W2  = (const float*)d_in[5];
    const float* b2  = (const float*)d_in[6];
    const float* Wm1 = (const float*)d_in[7];
    const float* bm1 = (const float*)d_in[8];
    const float* Wm2 = (const float*)d_in[9];
    const float* bm2 = (const float*)d_in[10];
    float* out = (float*)d_out;

    char* w = (char*)d_ws;
    int* dcur          = (int*)w;   w += (size_t)(NB + 4) * 4;
    int* scur          = (int*)w;   w += (size_t)(NB + 4) * 4;
    float* out_norm    = (float*)w; w += (size_t)NNODES * 4;
    float* in_norm     = (float*)w; w += (size_t)NNODES * 4;
    int2* row_span     = (int2*)w;  w += (size_t)NNODES * 8;
    int* csr_src       = (int*)w;   w += (size_t)NB * CAP * 4;
    unsigned* epk      = (unsigned*)w; w += (size_t)NB * CAP * 4;
    unsigned short* esl= (unsigned short*)w; w += (size_t)NB * CAP * 2;
    short8* Wp         = (short8*)w; w += (size_t)7168 * 16;
    unsigned* bufX     = (unsigned*)w; w += (size_t)NNODES * 64 * 4;
    unsigned* bufY     = (unsigned*)w; w += (size_t)NNODES * 64 * 4;

    init_cursors_kernel<<<1, 256, 0, stream>>>(dcur, scur);
    dual_bin_kernel<<<(NEDGES + T2 - 1) / T2, 256, 0, stream>>>(src, dst, dcur, scur, epk, esl);
    src_hist_kernel<<<NB, 512, 0, stream>>>(esl, scur, out_norm);
    bucket_csr_kernel<<<NB, 512, 0, stream>>>(epk, dcur, row_span, in_norm, csr_src);
    scale_slice_kernel<<<(NNODES * 64 + 255) / 256, 256, 0, stream>>>(x, out_norm, bufX);
    pack_all_kernel<<<28, 256, 0, stream>>>(W1, W2, Wm1, Wm2, Wp);

    const dim3 aggGrid(NNODES / 4, 8);
    const int gemmGrid = (NNODES + 63) / 64;

    // conv1: sliced agg (bufX) -> bufY (slice-major); gemm slice->slice, *out_norm
    aggregate_slice_kernel<<<aggGrid, 256, 0, stream>>>(bufX, row_span, csr_src, in_norm, bufY);
    gemm_mfma_kernel<1, 1><<<gemmGrid, 256, 0, stream>>>((const unsigned short*)bufY, Wp, b1, out_norm,
                                                         (unsigned short*)bufX, NNODES);
    // conv2: sliced agg (bufX) -> bufY; gemm slice->row (feeds MLP)
    aggregate_slice_kernel<<<aggGrid, 256, 0, stream>>>(bufX, row_span, csr_src, in_norm, bufY);
    gemm_mfma_kernel<0, 0><<<gemmGrid, 256, 0, stream>>>((const unsigned short*)bufY, Wp + 2048, b2, out_norm,
                                                         (unsigned short*)bufX, NNODES);
    mlp_fused_kernel<<<gemmGrid, 256, 0, stream>>>((const unsigned short*)bufX, Wp + 4096, bm1,
                                                   Wp + 6144, bm2, out, NNODES);
}

// Round 8
// 633.382 us; speedup vs baseline: 1.1716x; 1.1716x over previous
//
#include <hip/hip_runtime.h>
#include <math.h>

#define NNODES 100000
#define NEDGES 3200000
#define F 128
#define NPB 512
#define NB ((NNODES + NPB - 1) / NPB)   // 196 buckets
#define CAP 20480                        // slots per bucket (mean 16326, 32 sigma margin)
#define T2 8192

typedef __attribute__((ext_vector_type(8))) short short8;
typedef __attribute__((ext_vector_type(4))) float f32x4;

__device__ __forceinline__ unsigned short f2bf(float f) {
    unsigned u = __float_as_uint(f);
    unsigned r = u + 0x7fff + ((u >> 16) & 1);
    return (unsigned short)(r >> 16);
}
__device__ __forceinline__ float bflo(unsigned u) { return __uint_as_float(u << 16); }
__device__ __forceinline__ float bfhi(unsigned u) { return __uint_as_float(u & 0xffff0000u); }

// ---------------- cursor init (CAP-strided bucket bases) ----------------

__global__ void init_cursors_kernel(int* __restrict__ dcur, int* __restrict__ scur) {
    int b = blockIdx.x * 256 + threadIdx.x;
    if (b < NB) { dcur[b] = b * CAP; scur[b] = b * CAP; }
}

// ---------------- dual binning: one edge read -> dst-keyed + src-keyed bins ----------------

__global__ __launch_bounds__(256) void dual_bin_kernel(const int* __restrict__ src,
                                                       const int* __restrict__ dst,
                                                       int* __restrict__ dcur,
                                                       int* __restrict__ scur,
                                                       unsigned* __restrict__ epk,
                                                       unsigned short* __restrict__ esl) {
    __shared__ unsigned pk[T2];
    __shared__ unsigned short sl[T2];
    __shared__ unsigned char db[T2], sb[T2];
    __shared__ int dh[NB], dbase[NB], dlc[NB];
    __shared__ int sh[NB], sbase[NB], slc[NB];
    int t = threadIdx.x;
    for (int i = t; i < NB; i += 256) { dh[i] = 0; dlc[i] = 0; sh[i] = 0; slc[i] = 0; }
    __syncthreads();
    int e0 = blockIdx.x * T2;
    int n = min(T2, NEDGES - e0);
    for (int i = t; i < n; i += 256) {
        int s = src[e0 + i], d = dst[e0 + i];
        int bd = d >> 9, bs = s >> 9;
        pk[i] = (unsigned)s | ((unsigned)(d & 511) << 17);
        sl[i] = (unsigned short)(s & 511);
        db[i] = (unsigned char)bd;
        sb[i] = (unsigned char)bs;
        atomicAdd(&dh[bd], 1);
        atomicAdd(&sh[bs], 1);
    }
    __syncthreads();
    for (int b = t; b < NB; b += 256) {
        if (dh[b]) dbase[b] = atomicAdd(&dcur[b], dh[b]);
        if (sh[b]) sbase[b] = atomicAdd(&scur[b], sh[b]);
    }
    __syncthreads();
    for (int i = t; i < n; i += 256) {
        int b = db[i];
        epk[dbase[b] + atomicAdd(&dlc[b], 1)] = pk[i];
    }
    for (int i = t; i < n; i += 256) {
        int b = sb[i];
        esl[sbase[b] + atomicAdd(&slc[b], 1)] = sl[i];
    }
}

// ---------------- out-degree -> out_norm (per-bucket LDS histogram) ----------------

__global__ __launch_bounds__(512) void src_hist_kernel(const unsigned short* __restrict__ esl,
                                                       const int* __restrict__ scur,
                                                       float* __restrict__ out_norm) {
    __shared__ int cnt[NPB];
    int t = threadIdx.x, b = blockIdx.x;
    cnt[t] = 0;
    __syncthreads();
    int e0 = b * CAP, e1 = scur[b];
    for (int i = e0 + t; i < e1; i += 512) atomicAdd(&cnt[esl[i]], 1);
    __syncthreads();
    int node = b * NPB + t;
    if (node < NNODES) out_norm[node] = rsqrtf((float)max(cnt[t], 1));
}

// ---------------- per-bucket fine CSR + in_norm (all-LDS cursors) ----------------

__global__ __launch_bounds__(512) void bucket_csr_kernel(const unsigned* __restrict__ epk,
                                                         const int* __restrict__ dcur,
                                                         int2* __restrict__ row_span,
                                                         float* __restrict__ in_norm,
                                                         int* __restrict__ csr_src) {
    __shared__ int hist[NPB], off[NPB], lcur[NPB];
    int t = threadIdx.x, b = blockIdx.x;
    hist[t] = 0; lcur[t] = 0;
    __syncthreads();
    int e0 = b * CAP, e1 = dcur[b];
    for (int i = e0 + t; i < e1; i += 512)
        atomicAdd(&hist[epk[i] >> 17], 1);
    __syncthreads();
    int h = hist[t];
    off[t] = h;
    __syncthreads();
    for (int d = 1; d < NPB; d <<= 1) {
        int u = (t >= d) ? off[t - d] : 0;
        __syncthreads();
        off[t] += u;
        __syncthreads();
    }
    int excl = off[t] - h;
    int node = b * NPB + t;
    if (node < NNODES) {
        row_span[node] = make_int2(e0 + excl, e0 + excl + h);
        in_norm[node] = rsqrtf((float)max(h, 1));
    }
    __syncthreads();
    off[t] = excl;
    __syncthreads();
    for (int i = e0 + t; i < e1; i += 512) {
        unsigned p = epk[i];
        int dl = p >> 17;
        csr_src[e0 + off[dl] + atomicAdd(&lcur[dl], 1)] = (int)(p & 0x1FFFF);
    }
}

// ---------------- x * out_norm -> bf16, slice-major [8][N][8 uints] ----------------
// slice s, uint q of row = feats (16s+2q, 16s+2q+1)

__global__ __launch_bounds__(256) void scale_slice_kernel(const float* __restrict__ x,
                                                          const float* __restrict__ out_norm,
                                                          unsigned* __restrict__ hsS) {
    int tid = blockIdx.x * 256 + threadIdx.x;
    if (tid >= NNODES * 64) return;
    int row = tid >> 6, l = tid & 63;
    int s = l >> 3, q = l & 7;
    float nrm = out_norm[row];
    float2 v = *(const float2*)(x + (size_t)row * F + 2 * l);
    hsS[((size_t)s * NNODES + row) * 8 + q] =
        (unsigned)f2bf(v.x * nrm) | ((unsigned)f2bf(v.y * nrm) << 16);
}

// ---------------- pack all 4 weight matrices into MFMA B-fragments ----------------
// Bp[(c*4+s)*64+lane] = W[s*32+(lane>>4)*8+j][c*16+(lane&15)]

__global__ void pack_all_kernel(const float* __restrict__ W1, const float* __restrict__ W2,
                                const float* __restrict__ Wm1, const float* __restrict__ Wm2,
                                short8* __restrict__ Wp) {
    int idx = blockIdx.x * 256 + threadIdx.x;
    if (idx >= 7168) return;
    const float* W; int ncol, base;
    if (idx < 2048)      { W = W1;  ncol = 128; base = 0; }
    else if (idx < 4096) { W = W2;  ncol = 128; base = 2048; }
    else if (idx < 6144) { W = Wm1; ncol = 128; base = 4096; }
    else                 { W = Wm2; ncol = 64;  base = 6144; }
    int li = idx - base;
    int lane = li & 63, s = (li >> 6) & 3, c = li >> 8;
    int nn = c * 16 + (lane & 15);
    int k0 = s * 32 + (lane >> 4) * 8;
    short8 v;
#pragma unroll
    for (int j = 0; j < 8; j++) v[j] = (short)f2bf(W[(size_t)(k0 + j) * ncol + nn]);
    Wp[idx] = v;
}

// ---------------- sliced aggregation, group-per-node ----------------
// blockIdx.y = slice. Wave = 8 nodes; lane group g (8 lanes) owns node base+g
// entirely: no reduction, no per-edge clamp, coalesced 64-uint store.

__global__ __launch_bounds__(256) void aggregate_slice_kernel(const unsigned* __restrict__ hsS,
                                                              const int2* __restrict__ row_span,
                                                              const int* __restrict__ csr_src,
                                                              const float* __restrict__ in_norm,
                                                              unsigned* __restrict__ outS) {
    int wave = threadIdx.x >> 6;
    int lane = threadIdx.x & 63;
    int g = lane >> 3, q = lane & 7;
    int node = blockIdx.x * 32 + wave * 8 + g;
    int s = blockIdx.y;
    const unsigned* hs = hsS + (size_t)s * NNODES * 8;
    int2 sp = row_span[node];
    float a0 = 0.f, a1 = 0.f;
    int j = sp.x, end = sp.y;
    for (; j + 4 <= end; j += 4) {
        int s0 = csr_src[j], s1 = csr_src[j + 1], s2 = csr_src[j + 2], s3 = csr_src[j + 3];
        unsigned u0 = hs[(size_t)s0 * 8 + q];
        unsigned u1 = hs[(size_t)s1 * 8 + q];
        unsigned u2 = hs[(size_t)s2 * 8 + q];
        unsigned u3 = hs[(size_t)s3 * 8 + q];
        a0 += bflo(u0) + bflo(u1) + bflo(u2) + bflo(u3);
        a1 += bfhi(u0) + bfhi(u1) + bfhi(u2) + bfhi(u3);
    }
    for (; j < end; j++) {
        unsigned u = hs[(size_t)csr_src[j] * 8 + q];
        a0 += bflo(u);
        a1 += bfhi(u);
    }
    float inn = in_norm[node];
    outS[((size_t)s * NNODES + node) * 8 + q] =
        (unsigned)f2bf(a0 * inn) | ((unsigned)f2bf(a1 * inn) << 16);
}

// ---------------- MFMA GEMM: relu(A@W+b) [*out_norm]; A slice-major ----------------
// CSLICE: store slice-major (else row-major)

template <int SCALE, int CSLICE>
__global__ __launch_bounds__(256) void gemm_mfma_kernel(const unsigned short* __restrict__ A,
                                                        const short8* __restrict__ Bp,
                                                        const float* __restrict__ bias,
                                                        const float* __restrict__ out_norm,
                                                        unsigned short* __restrict__ Cout, int nrows) {
    int w = threadIdx.x >> 6, lane = threadIdx.x & 63;
    int m = lane & 15, quad = lane >> 4;
    int row0 = blockIdx.x * 64 + w * 16;

    int arow = min(row0 + m, nrows - 1);
    short8 afrag[4];
#pragma unroll
    for (int s = 0; s < 4; s++) {
        int sl = 2 * s + (quad >> 1);
        int off = (quad & 1) * 8;
        afrag[s] = *(const short8*)(A + ((size_t)sl * NNODES + arow) * 16 + off);
    }

    int baseRow = row0 + quad * 4;
    float nrm[4];
    if (SCALE) {
#pragma unroll
        for (int r = 0; r < 4; r++) nrm[r] = out_norm[min(baseRow + r, nrows - 1)];
    }

#pragma unroll
    for (int c = 0; c < 8; c++) {
        f32x4 acc = {0.f, 0.f, 0.f, 0.f};
#pragma unroll
        for (int s = 0; s < 4; s++) {
            short8 b = Bp[(c * 4 + s) * 64 + lane];
            acc = __builtin_amdgcn_mfma_f32_16x16x32_bf16(afrag[s], b, acc, 0, 0, 0);
        }
        float bc = bias[c * 16 + m];
#pragma unroll
        for (int r = 0; r < 4; r++) {
            int row = baseRow + r;
            if (row < nrows) {
                float v = fmaxf(acc[r] + bc, 0.f);
                if (SCALE) v *= nrm[r];
                if (CSLICE)
                    Cout[((size_t)c * NNODES + row) * 16 + m] = f2bf(v);
                else
                    Cout[(size_t)row * F + c * 16 + m] = f2bf(v);
            }
        }
    }
}

// ---------------- fused MLP head: sigmoid(relu(A@Wm1+bm1)@Wm2+bm2), A row-major ----------------

__global__ __launch_bounds__(256) void mlp_fused_kernel(const unsigned short* __restrict__ A,
                                                        const short8* __restrict__ Bp1,
                                                        const float* __restrict__ bm1,
                                                        const short8* __restrict__ Bp2,
                                                        const float* __restrict__ bm2,
                                                        float* __restrict__ out, int nrows) {
    __shared__ unsigned short h3[4][16][136];
    int w = threadIdx.x >> 6, lane = threadIdx.x & 63;
    int m = lane & 15, quad = lane >> 4;
    int row0 = blockIdx.x * 64 + w * 16;

    int arow = min(row0 + m, nrows - 1);
    short8 afrag[4];
#pragma unroll
    for (int s = 0; s < 4; s++)
        afrag[s] = *(const short8*)(A + (size_t)arow * F + s * 32 + quad * 8);

#pragma unroll
    for (int c = 0; c < 8; c++) {
        f32x4 acc = {0.f, 0.f, 0.f, 0.f};
#pragma unroll
        for (int s = 0; s < 4; s++) {
            short8 b = Bp1[(c * 4 + s) * 64 + lane];
            acc = __builtin_amdgcn_mfma_f32_16x16x32_bf16(afrag[s], b, acc, 0, 0, 0);
        }
        float bc = bm1[c * 16 + m];
#pragma unroll
        for (int r = 0; r < 4; r++)
            h3[w][quad * 4 + r][c * 16 + m] = f2bf(fmaxf(acc[r] + bc, 0.f));
    }
    __syncthreads();

    short8 a2[4];
#pragma unroll
    for (int s = 0; s < 4; s++)
        a2[s] = *(const short8*)(&h3[w][m][s * 32 + quad * 8]);

    int baseRow = row0 + quad * 4;
#pragma unroll
    for (int c2 = 0; c2 < 4; c2++) {
        f32x4 acc = {0.f, 0.f, 0.f, 0.f};
#pragma unroll
        for (int s = 0; s < 4; s++) {
            short8 b = Bp2[(c2 * 4 + s) * 64 + lane];
            acc = __builtin_amdgcn_mfma_f32_16x16x32_bf16(a2[s], b, acc, 0, 0, 0);
        }
        float bc = bm2[c2 * 16 + m];
#pragma unroll
        for (int r = 0; r < 4; r++) {
            int row = baseRow + r;
            if (row < nrows)
                out[(size_t)row * 64 + c2 * 16 + m] = 1.f / (1.f + __expf(-(acc[r] + bc)));
        }
    }
}

// ---------------- launch ----------------

extern "C" void kernel_launch(void* const* d_in, const int* in_sizes, int n_in,
                              void* d_out, int out_size, void* d_ws, size_t ws_size,
                              hipStream_t stream) {
    const float* x   = (const float*)d_in[0];
    const int* src   = (const int*)d_in[1];
    const int* dst   = (const int*)d_in[2];
    const float* W1  = (const float*)d_in[3];
    const float* b1  = (const float*)d_in[4];
    const float* W2  = (const float*)d_in[5];
    const float* b2  = (const float*)d_in[6];
    const float* Wm1 = (const float*)d_in[7];
    const float* bm1 = (const float*)d_in[8];
    const float* Wm2 = (const float*)d_in[9];
    const float* bm2 = (const float*)d_in[10];
    float* out = (float*)d_out;

    char* w = (char*)d_ws;
    int* dcur          = (int*)w;   w += (size_t)(NB + 4) * 4;
    int* scur          = (int*)w;   w += (size_t)(NB + 4) * 4;
    float* out_norm    = (float*)w; w += (size_t)NNODES * 4;
    float* in_norm     = (float*)w; w += (size_t)NNODES * 4;
    int2* row_span     = (int2*)w;  w += (size_t)NNODES * 8;
    int* csr_src       = (int*)w;   w += (size_t)NB * CAP * 4;
    unsigned* epk      = (unsigned*)w; w += (size_t)NB * CAP * 4;
    unsigned short* esl= (unsigned short*)w; w += (size_t)NB * CAP * 2;
    short8* Wp         = (short8*)w; w += (size_t)7168 * 16;
    unsigned* bufX     = (unsigned*)w; w += (size_t)NNODES * 64 * 4;
    unsigned* bufY     = (unsigned*)w; w += (size_t)NNODES * 64 * 4;

    init_cursors_kernel<<<1, 256, 0, stream>>>(dcur, scur);
    dual_bin_kernel<<<(NEDGES + T2 - 1) / T2, 256, 0, stream>>>(src, dst, dcur, scur, epk, esl);
    src_hist_kernel<<<NB, 512, 0, stream>>>(esl, scur, out_norm);
    bucket_csr_kernel<<<NB, 512, 0, stream>>>(epk, dcur, row_span, in_norm, csr_src);
    scale_slice_kernel<<<(NNODES * 64 + 255) / 256, 256, 0, stream>>>(x, out_norm, bufX);
    pack_all_kernel<<<28, 256, 0, stream>>>(W1, W2, Wm1, Wm2, Wp);

    const dim3 aggGrid(NNODES / 32, 8);   // 3125 x 8; 32 nodes/block
    const int gemmGrid = (NNODES + 63) / 64;

    // conv1: sliced agg (bufX) -> bufY (slice-major); gemm slice->slice, *out_norm
    aggregate_slice_kernel<<<aggGrid, 256, 0, stream>>>(bufX, row_span, csr_src, in_norm, bufY);
    gemm_mfma_kernel<1, 1><<<gemmGrid, 256, 0, stream>>>((const unsigned short*)bufY, Wp, b1, out_norm,
                                                         (unsigned short*)bufX, NNODES);
    // conv2: sliced agg (bufX) -> bufY; gemm slice->row (feeds MLP)
    aggregate_slice_kernel<<<aggGrid, 256, 0, stream>>>(bufX, row_span, csr_src, in_norm, bufY);
    gemm_mfma_kernel<0, 0><<<gemmGrid, 256, 0, stream>>>((const unsigned short*)bufY, Wp + 2048, b2, out_norm,
                                                         (unsigned short*)bufX, NNODES);
    mlp_fused_kernel<<<gemmGrid, 256, 0, stream>>>((const unsigned short*)bufX, Wp + 4096, bm1,
                                                   Wp + 6144, bm2, out, NNODES);
}